// Round 7
// baseline (1645.814 us; speedup 1.0000x reference)
//
#include <hip/hip_runtime.h>
#include <hip/hip_bf16.h>
#include <math.h>

typedef unsigned short u16t;
typedef unsigned int   u32t;

#define NPTS   8192
#define DMODEL 256
#define BNTOT  16384

__device__ __forceinline__ float bitsf(u32t u){ union { u32t i; float f; } v; v.i = u; return v.f; }
__device__ __forceinline__ float b2f(u16t s){ return bitsf(((u32t)s) << 16); }
__device__ __forceinline__ u16t f2b(float f){
  __hip_bfloat16 h = __float2bfloat16(f);
  return *reinterpret_cast<u16t*>(&h);
}
__device__ __forceinline__ uint4 pack8(const float* o){
  uint4 st;
  st.x = (u32t)f2b(o[0]) | ((u32t)f2b(o[1]) << 16);
  st.y = (u32t)f2b(o[2]) | ((u32t)f2b(o[3]) << 16);
  st.z = (u32t)f2b(o[4]) | ((u32t)f2b(o[5]) << 16);
  st.w = (u32t)f2b(o[6]) | ((u32t)f2b(o[7]) << 16);
  return st;
}
__device__ __forceinline__ float gelu_exact(float x){
  return 0.5f * x * (1.0f + erff(x * 0.70710678118654752f));
}

__global__ __launch_bounds__(256) void fill_valf(float* p, int n, float v){
  int i = blockIdx.x * 256 + threadIdx.x;
  if (i < n) p[i] = v;
}

// ---------------------------------------------------------------- kNN partial
// 4 candidate chunks of 2048; per-thread register top-16 (sorted, stable).
// Non-contracted f32 math to match the numpy distance formula.
__global__ __launch_bounds__(256) void knn_partial(const float* __restrict__ coords,
                                                   float* __restrict__ pd,
                                                   int* __restrict__ pi) {
  int qb = blockIdx.x >> 2, ch = blockIdx.x & 3;
  int tid = threadIdx.x;
  int g = qb * 256 + tid;
  int b = g >> 13;
  alignas(16) __shared__ float4 tile[256];

  float qx = coords[(size_t)g * 3 + 0];
  float qy = coords[(size_t)g * 3 + 1];
  float qz = coords[(size_t)g * 3 + 2];
  float qd2 = __fadd_rn(__fadd_rn(__fmul_rn(qx,qx), __fmul_rn(qy,qy)), __fmul_rn(qz,qz));

  float bd[16]; int bi[16];
  #pragma unroll
  for (int s = 0; s < 16; ++s) { bd[s] = 3e38f; bi[s] = 0x7fffffff; }

  int cs = ch * 2048;
  for (int t = 0; t < 8; ++t) {
    int ci = cs + t * 256 + tid;
    size_t cb = (size_t)(b * NPTS + ci) * 3;
    float x = coords[cb + 0];
    float y = coords[cb + 1];
    float z = coords[cb + 2];
    float d2 = __fadd_rn(__fadd_rn(__fmul_rn(x,x), __fmul_rn(y,y)), __fmul_rn(z,z));
    __syncthreads();
    tile[tid] = make_float4(x, y, z, d2);
    __syncthreads();
    int cbase = cs + t * 256;
    for (int u = 0; u < 256; ++u) {
      float4 cd = tile[u];
      float dot = __fadd_rn(__fadd_rn(__fmul_rn(qx,cd.x), __fmul_rn(qy,cd.y)), __fmul_rn(qz,cd.z));
      float dist = __fsub_rn(__fadd_rn(qd2, cd.w), __fmul_rn(2.0f, dot));
      if (dist < bd[15]) {
        bd[15] = dist; bi[15] = cbase + u;
        #pragma unroll
        for (int s = 15; s > 0; --s) {
          if (bd[s] < bd[s-1]) {
            float td = bd[s]; bd[s] = bd[s-1]; bd[s-1] = td;
            int   ti = bi[s]; bi[s] = bi[s-1]; bi[s-1] = ti;
          }
        }
      }
    }
  }
  size_t base = (size_t)g * 64 + ch * 16;
  #pragma unroll
  for (int s = 0; s < 16; ++s) { pd[base + s] = bd[s]; pi[base + s] = bi[s]; }
}

// ---------------------------------------------------------------- kNN merge
__global__ __launch_bounds__(256) void knn_merge(const float* __restrict__ pd,
                                                 const int* __restrict__ pi,
                                                 int* __restrict__ idxb) {
  int g = blockIdx.x * 256 + threadIdx.x;
  size_t base = (size_t)g * 64;
  int h0 = 0, h1 = 0, h2 = 0, h3 = 0;
  for (int s = 0; s < 16; ++s) {
    float bdv = 3.3e38f; int bix = 0x7fffffff; int bc = -1;
    int hh[4] = {h0, h1, h2, h3};
    #pragma unroll
    for (int c = 0; c < 4; ++c) {
      if (hh[c] < 16) {
        float dd = pd[base + c * 16 + hh[c]];
        int   ii = pi[base + c * 16 + hh[c]];
        if (dd < bdv || (dd == bdv && ii < bix)) { bdv = dd; bix = ii; bc = c; }
      }
    }
    idxb[(size_t)g * 16 + s] = bix;
    if (bc == 0) h0++; else if (bc == 1) h1++; else if (bc == 2) h2++; else h3++;
  }
}

// ----------------------------------------------------------------- K/V GEMM
// 128x128 tile, 8x8 per-thread register block; bf16 output (internal cache).
__global__ __launch_bounds__(256) void gemm_kv(const float* __restrict__ feat,
    const float* __restrict__ Wk, const float* __restrict__ bk,
    const float* __restrict__ Wv, const float* __restrict__ bv,
    u16t* __restrict__ kb, u16t* __restrict__ vb) {
  int mat = blockIdx.z;
  const float* W    = mat ? Wv : Wk;
  const float* bias = mat ? bv : bk;
  u16t* out         = mat ? vb : kb;

  int rbase = blockIdx.x * 128;
  int cbase = blockIdx.y * 128;
  int tid = threadIdx.x;
  int tx = tid & 15, ty = tid >> 4;

  alignas(16) __shared__ float xs[16][128];
  alignas(16) __shared__ float wsh[16][128];

  float acc[8][8];
  #pragma unroll
  for (int i = 0; i < 8; ++i)
    #pragma unroll
    for (int j = 0; j < 8; ++j) acc[i][j] = 0.0f;

  for (int k0 = 0; k0 < DMODEL; k0 += 16) {
    __syncthreads();
    {
      int r = tid >> 1, kk = (tid & 1) * 8;
      const float* src = feat + (size_t)(rbase + r) * DMODEL + k0 + kk;
      float4 u0 = *(const float4*)src;
      float4 u1 = *(const float4*)(src + 4);
      xs[kk+0][r]=u0.x; xs[kk+1][r]=u0.y; xs[kk+2][r]=u0.z; xs[kk+3][r]=u0.w;
      xs[kk+4][r]=u1.x; xs[kk+5][r]=u1.y; xs[kk+6][r]=u1.z; xs[kk+7][r]=u1.w;
    }
    {
      int kk = tid >> 4; int cc = (tid & 15) * 8;
      const float* src = W + (size_t)(k0 + kk) * DMODEL + cbase + cc;
      *(float4*)&wsh[kk][cc]     = *(const float4*)src;
      *(float4*)&wsh[kk][cc + 4] = *(const float4*)(src + 4);
    }
    __syncthreads();
    #pragma unroll
    for (int kk = 0; kk < 16; ++kk) {
      float a[8], bb[8];
      #pragma unroll
      for (int i = 0; i < 8; ++i) a[i]  = xs[kk][ty * 8 + i];
      #pragma unroll
      for (int j = 0; j < 8; ++j) bb[j] = wsh[kk][tx * 8 + j];
      #pragma unroll
      for (int i = 0; i < 8; ++i)
        #pragma unroll
        for (int j = 0; j < 8; ++j) acc[i][j] += a[i] * bb[j];
    }
  }

  float bbv[8];
  #pragma unroll
  for (int j = 0; j < 8; ++j) bbv[j] = bias[cbase + tx * 8 + j];
  #pragma unroll
  for (int ri = 0; ri < 8; ++ri) {
    size_t row = rbase + ty * 8 + ri;
    float o[8];
    #pragma unroll
    for (int j = 0; j < 8; ++j) o[j] = acc[ri][j] + bbv[j];
    *(uint4*)&out[row * DMODEL + cbase + tx * 8] = pack8(o);
  }
}

// -------------------------------------------------------------- mega kernel
// Block = 8 queries, thread = channel c. q on the fly; pos-MLP emb in regs;
// logits via width-32 shfl; softmax; PV -> oall LDS; batched out-proj;
// residual + LayerNorm; **f32 store to d_out**.
__global__ __launch_bounds__(256) void attn_mega(
    const float* __restrict__ coords, const float* __restrict__ normals,
    const float* __restrict__ maskp, const float* __restrict__ feat,
    const float* __restrict__ Wq, const float* __restrict__ bq,
    const float* __restrict__ Wp1, const float* __restrict__ bp1,
    const float* __restrict__ Wp2, const float* __restrict__ bp2,
    const float* __restrict__ Wo, const float* __restrict__ bo,
    const float* __restrict__ gamma, const float* __restrict__ beta,
    const int* __restrict__ idxb,
    const u16t* __restrict__ kbuf, const u16t* __restrict__ vbuf,
    float* __restrict__ outp) {
  alignas(16) __shared__ float hiddenf[DMODEL * 16];   // [i][j]  16 KB
  alignas(16) __shared__ float oall[8 * DMODEL];       // [qi][c]  8 KB
  alignas(16) __shared__ float featrow[DMODEL];
  alignas(16) __shared__ float lgs[8 * 16];
  __shared__ float red[4], red2[4];

  int c = threadIdx.x;
  int hh = c >> 5;

  float w1[6];
  #pragma unroll
  for (int p = 0; p < 6; ++p) w1[p] = Wp1[p * DMODEL + c];
  float b1v = bp1[c];
  float b2v = bp2[c];
  float bqv = bq[c];
  float bov = bo[c];
  float gam = gamma[c];
  float bet = beta[c];

  int qbase = blockIdx.x * 8;

  for (int qi = 0; qi < 8; ++qi) {
    int g = qbase + qi;
    int bb0 = (g >> 13) * NPTS;

    float qx = coords[(size_t)g * 3 + 0];
    float qy = coords[(size_t)g * 3 + 1];
    float qz = coords[(size_t)g * 3 + 2];
    float n0 = normals[(size_t)g * 3 + 0];
    float n1 = normals[(size_t)g * 3 + 1];
    float n2 = normals[(size_t)g * 3 + 2];

    int ids[16];
    float hreg[16];
    #pragma unroll
    for (int j = 0; j < 16; ++j) {
      int id = idxb[(size_t)g * 16 + j] & (NPTS - 1);
      ids[j] = id;
      size_t cb = (size_t)(bb0 + id) * 3;
      float rx = qx - coords[cb + 0];
      float ry = qy - coords[cb + 1];
      float rz = qz - coords[cb + 2];
      float pre = b1v + rx * w1[0] + ry * w1[1] + rz * w1[2]
                      + n0 * w1[3] + n1 * w1[4] + n2 * w1[5];
      hreg[j] = gelu_exact(pre);
    }

    __syncthreads();   // previous iteration's readers done
    featrow[c] = feat[(size_t)g * DMODEL + c];
    #pragma unroll
    for (int j = 0; j < 16; ++j) hiddenf[c * 16 + j] = hreg[j];
    __syncthreads();

    // q projection on the fly
    float qv = bqv;
    for (int d = 0; d < DMODEL; d += 4) {
      qv += featrow[d + 0] * Wq[(size_t)(d + 0) * DMODEL + c];
      qv += featrow[d + 1] * Wq[(size_t)(d + 1) * DMODEL + c];
      qv += featrow[d + 2] * Wq[(size_t)(d + 2) * DMODEL + c];
      qv += featrow[d + 3] * Wq[(size_t)(d + 3) * DMODEL + c];
    }

    // pos-MLP second layer: emb[j] for all 16 neighbours in registers
    float acc[16];
    #pragma unroll
    for (int j = 0; j < 16; ++j) acc[j] = b2v;
    for (int i = 0; i < DMODEL; ++i) {
      float w = Wp2[(size_t)i * DMODEL + c];
      const float4* hp = (const float4*)&hiddenf[i * 16];
      float4 h0 = hp[0], h1 = hp[1], h2 = hp[2], h3 = hp[3];
      acc[0]  += w * h0.x; acc[1]  += w * h0.y; acc[2]  += w * h0.z; acc[3]  += w * h0.w;
      acc[4]  += w * h1.x; acc[5]  += w * h1.y; acc[6]  += w * h1.z; acc[7]  += w * h1.w;
      acc[8]  += w * h2.x; acc[9]  += w * h2.y; acc[10] += w * h2.z; acc[11] += w * h2.w;
      acc[12] += w * h3.x; acc[13] += w * h3.y; acc[14] += w * h3.z; acc[15] += w * h3.w;
    }

    const float lsc = 0.17677669529663687f;
    #pragma unroll
    for (int j = 0; j < 16; ++j) {
      float kc = b2f(kbuf[(size_t)(bb0 + ids[j]) * DMODEL + c]) + acc[j];
      float p = qv * kc;
      p += __shfl_xor(p, 16, 32);
      p += __shfl_xor(p, 8, 32);
      p += __shfl_xor(p, 4, 32);
      p += __shfl_xor(p, 2, 32);
      p += __shfl_xor(p, 1, 32);
      if ((c & 31) == 0) {
        float mv = maskp[bb0 + ids[j]];
        lgs[hh * 16 + j] = (mv > 0.0f) ? (p * lsc) : -1e30f;
      }
    }
    __syncthreads();

    float lg[16];
    #pragma unroll
    for (int j = 0; j < 16; ++j) lg[j] = lgs[hh * 16 + j];
    float m = lg[0];
    #pragma unroll
    for (int j = 1; j < 16; ++j) m = fmaxf(m, lg[j]);
    float wj[16];
    if (m > -1e29f) {
      float s = 0.0f;
      #pragma unroll
      for (int j = 0; j < 16; ++j) { wj[j] = expf(lg[j] - m); s += wj[j]; }
      float inv = 1.0f / s;
      #pragma unroll
      for (int j = 0; j < 16; ++j) wj[j] *= inv;
    } else {
      #pragma unroll
      for (int j = 0; j < 16; ++j) wj[j] = 0.0f;
    }
    float o = 0.0f;
    #pragma unroll
    for (int j = 0; j < 16; ++j)
      o += wj[j] * (b2f(vbuf[(size_t)(bb0 + ids[j]) * DMODEL + c]) + acc[j]);
    oall[qi * DMODEL + c] = o;
  }
  __syncthreads();

  // batched out-projection
  float po[8];
  #pragma unroll
  for (int qi = 0; qi < 8; ++qi) po[qi] = 0.0f;
  for (int cc = 0; cc < DMODEL; ++cc) {
    float w = Wo[(size_t)cc * DMODEL + c];
    #pragma unroll
    for (int qi = 0; qi < 8; ++qi) po[qi] += w * oall[qi * DMODEL + cc];
  }

  // residual + LayerNorm + mask; f32 store
  for (int qi = 0; qi < 8; ++qi) {
    int g = qbase + qi;
    float mv = maskp[g];
    float h = feat[(size_t)g * DMODEL + c] + (po[qi] + bov) * mv;
    float s = h, s2 = h * h;
    #pragma unroll
    for (int off = 32; off > 0; off >>= 1) {
      s  += __shfl_down(s,  off);
      s2 += __shfl_down(s2, off);
    }
    __syncthreads();
    if ((c & 63) == 0) { red[c >> 6] = s; red2[c >> 6] = s2; }
    __syncthreads();
    float mu  = (red[0]  + red[1]  + red[2]  + red[3])  * (1.0f / 256.0f);
    float ms  = (red2[0] + red2[1] + red2[2] + red2[3]) * (1.0f / 256.0f);
    float var = ms - mu * mu;
    float y = (h - mu) / sqrtf(var + 1e-6f) * gam + bet;
    y *= mv;
    outp[(size_t)g * DMODEL + c] = y;
  }
}

// ---------------------------------------------------------------------- host
extern "C" void kernel_launch(void* const* d_in, const int* in_sizes, int n_in,
                              void* d_out, int out_size, void* d_ws, size_t ws_size,
                              hipStream_t stream) {
  static const int EXP[18] = {4194304, 49152, 49152, 16384,
                              65536, 256, 65536, 256, 65536, 256, 65536, 256,
                              1536, 256, 65536, 256, 256, 256};
  bool sizes_ok = (n_in >= 18);
  if (sizes_ok) for (int i = 0; i < 18; ++i) sizes_ok = sizes_ok && (in_sizes[i] == EXP[i]);
  int fb = (out_size + 255) / 256;
  if (!sizes_ok) {
    fill_valf<<<fb, 256, 0, stream>>>((float*)d_out, out_size, 0.0f);
    return;
  }
  const size_t WS_NEED = 17825792;
  if (ws_size < WS_NEED) {
    fill_valf<<<fb, 256, 0, stream>>>((float*)d_out, out_size, 1.0f);
    return;
  }

  const float* feat    = (const float*)d_in[0];
  const float* coords  = (const float*)d_in[1];
  const float* normals = (const float*)d_in[2];
  const float* maskp   = (const float*)d_in[3];
  const float* Wq  = (const float*)d_in[4];
  const float* bq  = (const float*)d_in[5];
  const float* Wk  = (const float*)d_in[6];
  const float* bk  = (const float*)d_in[7];
  const float* Wv  = (const float*)d_in[8];
  const float* bv  = (const float*)d_in[9];
  const float* Wo  = (const float*)d_in[10];
  const float* bo  = (const float*)d_in[11];
  const float* Wp1 = (const float*)d_in[12];
  const float* bp1 = (const float*)d_in[13];
  const float* Wp2 = (const float*)d_in[14];
  const float* bp2 = (const float*)d_in[15];
  const float* gamma = (const float*)d_in[16];
  const float* beta  = (const float*)d_in[17];

  char* ws = (char*)d_ws;
  int*   idxb = (int*)(ws);
  u16t*  kb   = (u16t*)(ws + 1048576);
  u16t*  vb   = (u16t*)(ws + 9437184);
  float* pd   = (float*)(ws + 1048576);   // alias over kb (dead after knn_merge)
  int*   pi   = (int*)(ws + 5242880);

  knn_partial<<<256, 256, 0, stream>>>(coords, pd, pi);
  knn_merge<<<64, 256, 0, stream>>>(pd, pi, idxb);
  gemm_kv<<<dim3(128, 2, 2), 256, 0, stream>>>(feat, Wk, bk, Wv, bv, kb, vb);
  attn_mega<<<2048, 256, 0, stream>>>(coords, normals, maskp, feat,
                                      Wq, bq, Wp1, bp1, Wp2, bp2, Wo, bo,
                                      gamma, beta, idxb, kb, vb,
                                      (float*)d_out);
}

// Round 8
// 1085.431 us; speedup vs baseline: 1.5163x; 1.5163x over previous
//
#include <hip/hip_runtime.h>
#include <hip/hip_bf16.h>
#include <math.h>

typedef unsigned short u16t;
typedef unsigned int   u32t;
typedef __attribute__((ext_vector_type(8))) short  short8;   // 8 bf16 (4 VGPRs)
typedef __attribute__((ext_vector_type(4))) float  floatx4;  // MFMA acc

#define NPTS   8192
#define DMODEL 256
#define BNTOT  16384

__device__ __forceinline__ float bitsf(u32t u){ union { u32t i; float f; } v; v.i = u; return v.f; }
__device__ __forceinline__ float b2f(u16t s){ return bitsf(((u32t)s) << 16); }
__device__ __forceinline__ u16t f2b(float f){
  __hip_bfloat16 h = __float2bfloat16(f);
  return *reinterpret_cast<u16t*>(&h);
}
__device__ __forceinline__ uint4 pack8(const float* o){
  uint4 st;
  st.x = (u32t)f2b(o[0]) | ((u32t)f2b(o[1]) << 16);
  st.y = (u32t)f2b(o[2]) | ((u32t)f2b(o[3]) << 16);
  st.z = (u32t)f2b(o[4]) | ((u32t)f2b(o[5]) << 16);
  st.w = (u32t)f2b(o[6]) | ((u32t)f2b(o[7]) << 16);
  return st;
}
__device__ __forceinline__ float gelu_exact(float x){
  return 0.5f * x * (1.0f + erff(x * 0.70710678118654752f));
}

__global__ __launch_bounds__(256) void fill_valf(float* p, int n, float v){
  int i = blockIdx.x * 256 + threadIdx.x;
  if (i < n) p[i] = v;
}

// ---------------------------------------------------------------- kNN partial
__global__ __launch_bounds__(256) void knn_partial(const float* __restrict__ coords,
                                                   float* __restrict__ pd,
                                                   int* __restrict__ pi) {
  int qb = blockIdx.x >> 2, ch = blockIdx.x & 3;
  int tid = threadIdx.x;
  int g = qb * 256 + tid;
  int b = g >> 13;
  alignas(16) __shared__ float4 tile[256];

  float qx = coords[(size_t)g * 3 + 0];
  float qy = coords[(size_t)g * 3 + 1];
  float qz = coords[(size_t)g * 3 + 2];
  float qd2 = __fadd_rn(__fadd_rn(__fmul_rn(qx,qx), __fmul_rn(qy,qy)), __fmul_rn(qz,qz));

  float bd[16]; int bi[16];
  #pragma unroll
  for (int s = 0; s < 16; ++s) { bd[s] = 3e38f; bi[s] = 0x7fffffff; }

  int cs = ch * 2048;
  for (int t = 0; t < 8; ++t) {
    int ci = cs + t * 256 + tid;
    size_t cb = (size_t)(b * NPTS + ci) * 3;
    float x = coords[cb + 0];
    float y = coords[cb + 1];
    float z = coords[cb + 2];
    float d2 = __fadd_rn(__fadd_rn(__fmul_rn(x,x), __fmul_rn(y,y)), __fmul_rn(z,z));
    __syncthreads();
    tile[tid] = make_float4(x, y, z, d2);
    __syncthreads();
    int cbase = cs + t * 256;
    for (int u = 0; u < 256; ++u) {
      float4 cd = tile[u];
      float dot = __fadd_rn(__fadd_rn(__fmul_rn(qx,cd.x), __fmul_rn(qy,cd.y)), __fmul_rn(qz,cd.z));
      float dist = __fsub_rn(__fadd_rn(qd2, cd.w), __fmul_rn(2.0f, dot));
      if (dist < bd[15]) {
        bd[15] = dist; bi[15] = cbase + u;
        #pragma unroll
        for (int s = 15; s > 0; --s) {
          if (bd[s] < bd[s-1]) {
            float td = bd[s]; bd[s] = bd[s-1]; bd[s-1] = td;
            int   ti = bi[s]; bi[s] = bi[s-1]; bi[s-1] = ti;
          }
        }
      }
    }
  }
  size_t base = (size_t)g * 64 + ch * 16;
  #pragma unroll
  for (int s = 0; s < 16; ++s) { pd[base + s] = bd[s]; pi[base + s] = bi[s]; }
}

// ---------------------------------------------------------------- kNN merge
__global__ __launch_bounds__(256) void knn_merge(const float* __restrict__ pd,
                                                 const int* __restrict__ pi,
                                                 u16t* __restrict__ idxb) {
  int g = blockIdx.x * 256 + threadIdx.x;
  size_t base = (size_t)g * 64;
  int h0 = 0, h1 = 0, h2 = 0, h3 = 0;
  for (int s = 0; s < 16; ++s) {
    float bdv = 3.3e38f; int bix = 0x7fffffff; int bc = -1;
    int hh[4] = {h0, h1, h2, h3};
    #pragma unroll
    for (int c = 0; c < 4; ++c) {
      if (hh[c] < 16) {
        float dd = pd[base + c * 16 + hh[c]];
        int   ii = pi[base + c * 16 + hh[c]];
        if (dd < bdv || (dd == bdv && ii < bix)) { bdv = dd; bix = ii; bc = c; }
      }
    }
    idxb[(size_t)g * 16 + s] = (u16t)bix;
    if (bc == 0) h0++; else if (bc == 1) h1++; else if (bc == 2) h2++; else h3++;
  }
}

// ------------------------------------------------- Wp2 -> B-fragment packing
// wp2frag element ((ic*16+ccAbs)*64 + lane)*8 + v  =  Wp2[ic*32+(lane>>4)*8+v][ccAbs*16+(lane&15)]
__global__ __launch_bounds__(256) void wp2prep(const float* __restrict__ Wp2,
                                               u16t* __restrict__ wp2frag) {
  int e = blockIdx.x * 256 + threadIdx.x;      // 0..65535
  int v = e & 7, l = (e >> 3) & 63, cca = (e >> 9) & 15, ic = e >> 13;
  int i = ic * 32 + (l >> 4) * 8 + v;
  int c = cca * 16 + (l & 15);
  wp2frag[e] = f2b(Wp2[(size_t)i * DMODEL + c]);
}

// ----------------------------------------------------------------- K/V GEMM
__global__ __launch_bounds__(256) void gemm_kv(const float* __restrict__ feat,
    const float* __restrict__ Wk, const float* __restrict__ bk,
    const float* __restrict__ Wv, const float* __restrict__ bv,
    u16t* __restrict__ kb, u16t* __restrict__ vb) {
  int mat = blockIdx.z;
  const float* W    = mat ? Wv : Wk;
  const float* bias = mat ? bv : bk;
  u16t* out         = mat ? vb : kb;

  int rbase = blockIdx.x * 128;
  int cbase = blockIdx.y * 128;
  int tid = threadIdx.x;
  int tx = tid & 15, ty = tid >> 4;

  alignas(16) __shared__ float xs[16][128];
  alignas(16) __shared__ float wsh[16][128];

  float acc[8][8];
  #pragma unroll
  for (int i = 0; i < 8; ++i)
    #pragma unroll
    for (int j = 0; j < 8; ++j) acc[i][j] = 0.0f;

  for (int k0 = 0; k0 < DMODEL; k0 += 16) {
    __syncthreads();
    {
      int r = tid >> 1, kk = (tid & 1) * 8;
      const float* src = feat + (size_t)(rbase + r) * DMODEL + k0 + kk;
      float4 u0 = *(const float4*)src;
      float4 u1 = *(const float4*)(src + 4);
      xs[kk+0][r]=u0.x; xs[kk+1][r]=u0.y; xs[kk+2][r]=u0.z; xs[kk+3][r]=u0.w;
      xs[kk+4][r]=u1.x; xs[kk+5][r]=u1.y; xs[kk+6][r]=u1.z; xs[kk+7][r]=u1.w;
    }
    {
      int kk = tid >> 4; int cc = (tid & 15) * 8;
      const float* src = W + (size_t)(k0 + kk) * DMODEL + cbase + cc;
      *(float4*)&wsh[kk][cc]     = *(const float4*)src;
      *(float4*)&wsh[kk][cc + 4] = *(const float4*)(src + 4);
    }
    __syncthreads();
    #pragma unroll
    for (int kk = 0; kk < 16; ++kk) {
      float a[8], bb[8];
      #pragma unroll
      for (int i = 0; i < 8; ++i) a[i]  = xs[kk][ty * 8 + i];
      #pragma unroll
      for (int j = 0; j < 8; ++j) bb[j] = wsh[kk][tx * 8 + j];
      #pragma unroll
      for (int i = 0; i < 8; ++i)
        #pragma unroll
        for (int j = 0; j < 8; ++j) acc[i][j] += a[i] * bb[j];
    }
  }

  float bbv[8];
  #pragma unroll
  for (int j = 0; j < 8; ++j) bbv[j] = bias[cbase + tx * 8 + j];
  #pragma unroll
  for (int ri = 0; ri < 8; ++ri) {
    size_t row = rbase + ty * 8 + ri;
    float o[8];
    #pragma unroll
    for (int j = 0; j < 8; ++j) o[j] = acc[ri][j] + bbv[j];
    *(uint4*)&out[row * DMODEL + cbase + tx * 8] = pack8(o);
  }
}

// -------------------------------------------------------------- mega kernel
// v2: MFMA emb GEMM (bf16), block-amortized Wq/Wo reads, register B-frags.
// Block = 256 threads (4 waves) = 8 queries; thread = channel c.
#define HSTR 264   // hidT/embS row stride in bf16 (16B-aligned rows)
__global__ __launch_bounds__(256, 2) void attn_mega(
    const float* __restrict__ coords, const float* __restrict__ normals,
    const float* __restrict__ maskp, const float* __restrict__ feat,
    const float* __restrict__ Wq, const float* __restrict__ bq,
    const float* __restrict__ Wp1, const float* __restrict__ bp1,
    const float* __restrict__ bp2,
    const float* __restrict__ Wo, const float* __restrict__ bo,
    const float* __restrict__ gamma, const float* __restrict__ beta,
    const u16t* __restrict__ idxp, const u16t* __restrict__ wp2frag,
    const u16t* __restrict__ kbuf, const u16t* __restrict__ vbuf,
    float* __restrict__ outp) {
  alignas(16) __shared__ u16t  hemb[16 * HSTR];     // hidT[j][i] then embS[j][c] (aliased)
  alignas(16) __shared__ float featall[8 * DMODEL];
  alignas(16) __shared__ float oall[8 * DMODEL];
  alignas(16) __shared__ float lgs[8 * 16];
  __shared__ float red[4], red2[4];

  int c    = threadIdx.x;
  int lane = c & 63;
  int wv   = c >> 6;          // wave id 0..3
  int quad = lane >> 4;
  int l15  = lane & 15;
  int hh   = c >> 5;          // attention head of channel c

  // --- B fragments for this wave's 4 c-chunks, all 8 K-chunks (held in regs)
  short8 bfrag[4][8];
  #pragma unroll
  for (int cc = 0; cc < 4; ++cc)
    #pragma unroll
    for (int ic = 0; ic < 8; ++ic)
      bfrag[cc][ic] = *(const short8*)(wp2frag + (((size_t)(ic*16 + wv*4 + cc)*64 + lane) << 3));

  float w1[6];
  #pragma unroll
  for (int p = 0; p < 6; ++p) w1[p] = Wp1[p * DMODEL + c];
  float b1v = bp1[c];
  float b2v = bp2[c];
  float bqv = bq[c];
  float bov = bo[c];
  float gam = gamma[c];
  float bet = beta[c];

  int qbase = blockIdx.x * 8;

  // --- stage feat rows for the 8 queries
  #pragma unroll
  for (int qi = 0; qi < 8; ++qi)
    featall[qi * DMODEL + c] = feat[(size_t)(qbase + qi) * DMODEL + c];
  __syncthreads();

  // --- q projection for all 8 queries (Wq read once per block)
  float qreg[8];
  #pragma unroll
  for (int qi = 0; qi < 8; ++qi) qreg[qi] = bqv;
  for (int d = 0; d < DMODEL; d += 4) {
    float wa = Wq[(size_t)(d + 0) * DMODEL + c];
    float wb = Wq[(size_t)(d + 1) * DMODEL + c];
    float wc = Wq[(size_t)(d + 2) * DMODEL + c];
    float wd = Wq[(size_t)(d + 3) * DMODEL + c];
    #pragma unroll
    for (int qi = 0; qi < 8; ++qi) {
      qreg[qi] += featall[qi * DMODEL + d + 0] * wa;
      qreg[qi] += featall[qi * DMODEL + d + 1] * wb;
      qreg[qi] += featall[qi * DMODEL + d + 2] * wc;
      qreg[qi] += featall[qi * DMODEL + d + 3] * wd;
    }
  }

  const float lsc = 0.17677669529663687f;

  for (int qi = 0; qi < 8; ++qi) {
    int g = qbase + qi;
    int bb0 = (g >> 13) * NPTS;

    float qx = coords[(size_t)g * 3 + 0];
    float qy = coords[(size_t)g * 3 + 1];
    float qz = coords[(size_t)g * 3 + 2];
    float n0 = normals[(size_t)g * 3 + 0];
    float n1 = normals[(size_t)g * 3 + 1];
    float n2 = normals[(size_t)g * 3 + 2];

    int ids[16];
    float hreg[16];
    #pragma unroll
    for (int j = 0; j < 16; ++j) {
      int id = (int)idxp[(size_t)g * 16 + j];
      ids[j] = id;
      size_t cb = (size_t)(bb0 + id) * 3;
      float rx = qx - coords[cb + 0];
      float ry = qy - coords[cb + 1];
      float rz = qz - coords[cb + 2];
      float pre = b1v + rx * w1[0] + ry * w1[1] + rz * w1[2]
                      + n0 * w1[3] + n1 * w1[4] + n2 * w1[5];
      hreg[j] = gelu_exact(pre);
    }

    __syncthreads();   // sync1: previous query's hemb/lgs readers done
    // hidT[j][i=c] bf16
    #pragma unroll
    for (int j = 0; j < 16; ++j) hemb[j * HSTR + c] = f2b(hreg[j]);
    __syncthreads();   // sync2

    // A fragments: lane reads hidT[j=l15][ic*32 + quad*8 .. +7]
    short8 afrag[8];
    {
      const u16t* ap = hemb + l15 * HSTR + quad * 8;
      #pragma unroll
      for (int ic = 0; ic < 8; ++ic) afrag[ic] = *(const short8*)(ap + ic * 32);
    }
    __syncthreads();   // sync3: all hidT reads done (hemb about to be reused)

    // emb = hidden @ Wp2 via MFMA
    floatx4 acc[4];
    #pragma unroll
    for (int cc = 0; cc < 4; ++cc) acc[cc] = (floatx4){0.f, 0.f, 0.f, 0.f};
    #pragma unroll
    for (int ic = 0; ic < 8; ++ic) {
      #pragma unroll
      for (int cc = 0; cc < 4; ++cc)
        acc[cc] = __builtin_amdgcn_mfma_f32_16x16x32_bf16(afrag[ic], bfrag[cc][ic], acc[cc], 0, 0, 0);
    }
    // embS[j][c] bf16 (C-layout: col=lane&15, row=quad*4+reg)
    #pragma unroll
    for (int cc = 0; cc < 4; ++cc) {
      int cg = (wv * 4 + cc) * 16 + l15;
      #pragma unroll
      for (int r = 0; r < 4; ++r)
        hemb[(quad * 4 + r) * HSTR + cg] = f2b(acc[cc][r]);
    }
    __syncthreads();   // sync4

    float emb[16];
    #pragma unroll
    for (int j = 0; j < 16; ++j) emb[j] = b2f(hemb[j * HSTR + c]) + b2v;

    // logits via per-head shuffle reduction
    float qv = qreg[qi];
    #pragma unroll
    for (int j = 0; j < 16; ++j) {
      float kc = b2f(kbuf[(size_t)(bb0 + ids[j]) * DMODEL + c]) + emb[j];
      float p = qv * kc;
      p += __shfl_xor(p, 16, 32);
      p += __shfl_xor(p, 8, 32);
      p += __shfl_xor(p, 4, 32);
      p += __shfl_xor(p, 2, 32);
      p += __shfl_xor(p, 1, 32);
      if ((c & 31) == 0) {
        float mv = maskp[bb0 + ids[j]];
        lgs[hh * 16 + j] = (mv > 0.0f) ? (p * lsc) : -1e30f;
      }
    }
    __syncthreads();   // sync5

    float lg[16];
    #pragma unroll
    for (int j = 0; j < 16; ++j) lg[j] = lgs[hh * 16 + j];
    float m = lg[0];
    #pragma unroll
    for (int j = 1; j < 16; ++j) m = fmaxf(m, lg[j]);
    float wj[16];
    if (m > -1e29f) {
      float s = 0.0f;
      #pragma unroll
      for (int j = 0; j < 16; ++j) { wj[j] = expf(lg[j] - m); s += wj[j]; }
      float inv = 1.0f / s;
      #pragma unroll
      for (int j = 0; j < 16; ++j) wj[j] *= inv;
    } else {
      #pragma unroll
      for (int j = 0; j < 16; ++j) wj[j] = 0.0f;
    }
    float o = 0.0f;
    #pragma unroll
    for (int j = 0; j < 16; ++j)
      o += wj[j] * (b2f(vbuf[(size_t)(bb0 + ids[j]) * DMODEL + c]) + emb[j]);
    oall[qi * DMODEL + c] = o;
  }
  __syncthreads();

  // --- out projection (Wo read once per block)
  float po[8];
  #pragma unroll
  for (int qi = 0; qi < 8; ++qi) po[qi] = 0.0f;
  for (int d = 0; d < DMODEL; d += 4) {
    float wa = Wo[(size_t)(d + 0) * DMODEL + c];
    float wb = Wo[(size_t)(d + 1) * DMODEL + c];
    float wc = Wo[(size_t)(d + 2) * DMODEL + c];
    float wd = Wo[(size_t)(d + 3) * DMODEL + c];
    #pragma unroll
    for (int qi = 0; qi < 8; ++qi) {
      po[qi] += oall[qi * DMODEL + d + 0] * wa;
      po[qi] += oall[qi * DMODEL + d + 1] * wb;
      po[qi] += oall[qi * DMODEL + d + 2] * wc;
      po[qi] += oall[qi * DMODEL + d + 3] * wd;
    }
  }

  // --- residual + LayerNorm + mask; f32 store
  for (int qi = 0; qi < 8; ++qi) {
    int g = qbase + qi;
    float mv = maskp[g];
    float h = featall[qi * DMODEL + c] + (po[qi] + bov) * mv;
    float s = h, s2 = h * h;
    #pragma unroll
    for (int off = 32; off > 0; off >>= 1) {
      s  += __shfl_down(s,  off);
      s2 += __shfl_down(s2, off);
    }
    __syncthreads();
    if ((c & 63) == 0) { red[c >> 6] = s; red2[c >> 6] = s2; }
    __syncthreads();
    float mu  = (red[0]  + red[1]  + red[2]  + red[3])  * (1.0f / 256.0f);
    float ms  = (red2[0] + red2[1] + red2[2] + red2[3]) * (1.0f / 256.0f);
    float var = ms - mu * mu;
    float y = (h - mu) / sqrtf(var + 1e-6f) * gam + bet;
    y *= mv;
    outp[(size_t)g * DMODEL + c] = y;
  }
}

// ---------------------------------------------------------------------- host
extern "C" void kernel_launch(void* const* d_in, const int* in_sizes, int n_in,
                              void* d_out, int out_size, void* d_ws, size_t ws_size,
                              hipStream_t stream) {
  static const int EXP[18] = {4194304, 49152, 49152, 16384,
                              65536, 256, 65536, 256, 65536, 256, 65536, 256,
                              1536, 256, 65536, 256, 256, 256};
  bool sizes_ok = (n_in >= 18);
  if (sizes_ok) for (int i = 0; i < 18; ++i) sizes_ok = sizes_ok && (in_sizes[i] == EXP[i]);
  int fb = (out_size + 255) / 256;
  if (!sizes_ok) {
    fill_valf<<<fb, 256, 0, stream>>>((float*)d_out, out_size, 0.0f);
    return;
  }
  const size_t WS_NEED = 17825792;
  if (ws_size < WS_NEED) {
    fill_valf<<<fb, 256, 0, stream>>>((float*)d_out, out_size, 1.0f);
    return;
  }

  const float* feat    = (const float*)d_in[0];
  const float* coords  = (const float*)d_in[1];
  const float* normals = (const float*)d_in[2];
  const float* maskp   = (const float*)d_in[3];
  const float* Wq  = (const float*)d_in[4];
  const float* bq  = (const float*)d_in[5];
  const float* Wk  = (const float*)d_in[6];
  const float* bk  = (const float*)d_in[7];
  const float* Wv  = (const float*)d_in[8];
  const float* bv  = (const float*)d_in[9];
  const float* Wo  = (const float*)d_in[10];
  const float* bo  = (const float*)d_in[11];
  const float* Wp1 = (const float*)d_in[12];
  const float* bp1 = (const float*)d_in[13];
  const float* Wp2 = (const float*)d_in[14];
  const float* bp2 = (const float*)d_in[15];
  const float* gamma = (const float*)d_in[16];
  const float* beta  = (const float*)d_in[17];

  // Workspace (17 MB, WS_NEED unchanged):
  //   idx16   : u16  [16384*16]  @ 0          (524,288 B)
  //   wp2frag : bf16 [65536]     @ 524,288    (131,072 B)
  //   kb      : bf16 [16384*256] @ 1,048,576  (8,388,608 B)
  //   vb      : bf16 [16384*256] @ 9,437,184  (8,388,608 B)
  //   pd/pi (kNN partials, 8 MB) alias kb/vb: dead before gemm_kv runs.
  char* ws = (char*)d_ws;
  u16t*  idx16   = (u16t*)(ws);
  u16t*  wp2frag = (u16t*)(ws + 524288);
  u16t*  kb      = (u16t*)(ws + 1048576);
  u16t*  vb      = (u16t*)(ws + 9437184);
  float* pd      = (float*)(ws + 1048576);
  int*   pi      = (int*)(ws + 5242880);

  wp2prep<<<256, 256, 0, stream>>>(Wp2, wp2frag);
  knn_partial<<<256, 256, 0, stream>>>(coords, pd, pi);
  knn_merge<<<64, 256, 0, stream>>>(pd, pi, idx16);
  gemm_kv<<<dim3(128, 2, 2), 256, 0, stream>>>(feat, Wk, bk, Wv, bv, kb, vb);
  attn_mega<<<2048, 256, 0, stream>>>(coords, normals, maskp, feat,
                                      Wq, bq, Wp1, bp1, bp2, Wo, bo,
                                      gamma, beta, idx16, wp2frag, kb, vb,
                                      (float*)d_out);
}

// Round 9
// 1064.634 us; speedup vs baseline: 1.5459x; 1.0195x over previous
//
#include <hip/hip_runtime.h>
#include <hip/hip_bf16.h>
#include <math.h>

typedef unsigned short u16t;
typedef unsigned int   u32t;
typedef __attribute__((ext_vector_type(8))) short  short8;   // 8 bf16 (4 VGPRs)
typedef __attribute__((ext_vector_type(4))) float  floatx4;  // MFMA acc

#define NPTS   8192
#define DMODEL 256
#define BNTOT  16384

__device__ __forceinline__ float bitsf(u32t u){ union { u32t i; float f; } v; v.i = u; return v.f; }
__device__ __forceinline__ float b2f(u16t s){ return bitsf(((u32t)s) << 16); }
__device__ __forceinline__ u16t f2b(float f){
  __hip_bfloat16 h = __float2bfloat16(f);
  return *reinterpret_cast<u16t*>(&h);
}
__device__ __forceinline__ uint4 pack8(const float* o){
  uint4 st;
  st.x = (u32t)f2b(o[0]) | ((u32t)f2b(o[1]) << 16);
  st.y = (u32t)f2b(o[2]) | ((u32t)f2b(o[3]) << 16);
  st.z = (u32t)f2b(o[4]) | ((u32t)f2b(o[5]) << 16);
  st.w = (u32t)f2b(o[6]) | ((u32t)f2b(o[7]) << 16);
  return st;
}
__device__ __forceinline__ float gelu_exact(float x){
  return 0.5f * x * (1.0f + erff(x * 0.70710678118654752f));
}

__global__ __launch_bounds__(256) void fill_valf(float* p, int n, float v){
  int i = blockIdx.x * 256 + threadIdx.x;
  if (i < n) p[i] = v;
}

// -------------------------------------------------- weight fragment prepack
// frag element ((ic*16+cca)*64 + lane)*8 + v = W[ic*32+(lane>>4)*8+v][cca*16+(lane&15)]
// mats: 0=Wk, 1=Wv, 2=Wp2 (layout verified by round-8 pass)
__global__ __launch_bounds__(256) void wprep(const float* __restrict__ Wk,
                                             const float* __restrict__ Wv,
                                             const float* __restrict__ Wp2,
                                             u16t* __restrict__ frags) {
  int e = blockIdx.x * 256 + threadIdx.x;        // 0..196607
  int m = e >> 16, r = e & 65535;
  const float* W = (m == 0) ? Wk : (m == 1 ? Wv : Wp2);
  int v = r & 7, l = (r >> 3) & 63, cca = (r >> 9) & 15, ic = r >> 13;
  int i = ic * 32 + (l >> 4) * 8 + v;
  int c = cca * 16 + (l & 15);
  frags[(size_t)m * 65536 + r] = f2b(W[(size_t)i * DMODEL + c]);
}

// ---------------------------------------------------------------- kNN partial
// 8 candidate chunks of 1024 (grid 512 = 2 blocks/CU); register top-16, stable.
__global__ __launch_bounds__(256) void knn_partial(const float* __restrict__ coords,
                                                   float* __restrict__ pd,
                                                   int* __restrict__ pi) {
  int qb = blockIdx.x >> 3, ch = blockIdx.x & 7;
  int tid = threadIdx.x;
  int g = qb * 256 + tid;
  int b = g >> 13;
  alignas(16) __shared__ float4 tile[256];

  float qx = coords[(size_t)g * 3 + 0];
  float qy = coords[(size_t)g * 3 + 1];
  float qz = coords[(size_t)g * 3 + 2];
  float qd2 = __fadd_rn(__fadd_rn(__fmul_rn(qx,qx), __fmul_rn(qy,qy)), __fmul_rn(qz,qz));

  float bd[16]; int bi[16];
  #pragma unroll
  for (int s = 0; s < 16; ++s) { bd[s] = 3e38f; bi[s] = 0x7fffffff; }

  int cs = ch * 1024;
  for (int t = 0; t < 4; ++t) {
    int ci = cs + t * 256 + tid;
    size_t cb = (size_t)(b * NPTS + ci) * 3;
    float x = coords[cb + 0];
    float y = coords[cb + 1];
    float z = coords[cb + 2];
    float d2 = __fadd_rn(__fadd_rn(__fmul_rn(x,x), __fmul_rn(y,y)), __fmul_rn(z,z));
    __syncthreads();
    tile[tid] = make_float4(x, y, z, d2);
    __syncthreads();
    int cbase = cs + t * 256;
    for (int u = 0; u < 256; ++u) {
      float4 cd = tile[u];
      float dot = __fadd_rn(__fadd_rn(__fmul_rn(qx,cd.x), __fmul_rn(qy,cd.y)), __fmul_rn(qz,cd.z));
      float dist = __fsub_rn(__fadd_rn(qd2, cd.w), __fmul_rn(2.0f, dot));
      if (dist < bd[15]) {
        bd[15] = dist; bi[15] = cbase + u;
        #pragma unroll
        for (int s = 15; s > 0; --s) {
          if (bd[s] < bd[s-1]) {
            float td = bd[s]; bd[s] = bd[s-1]; bd[s-1] = td;
            int   ti = bi[s]; bi[s] = bi[s-1]; bi[s-1] = ti;
          }
        }
      }
    }
  }
  size_t base = (size_t)g * 128 + ch * 16;
  #pragma unroll
  for (int s = 0; s < 16; ++s) { pd[base + s] = bd[s]; pi[base + s] = bi[s]; }
}

// ---------------------------------------------------------------- kNN merge
// 8 sorted lists of 16 -> stable global top-16.
__global__ __launch_bounds__(256) void knn_merge(const float* __restrict__ pd,
                                                 const int* __restrict__ pi,
                                                 u16t* __restrict__ idxb) {
  int g = blockIdx.x * 256 + threadIdx.x;
  size_t base = (size_t)g * 128;
  int h[8];
  #pragma unroll
  for (int c = 0; c < 8; ++c) h[c] = 0;
  for (int s = 0; s < 16; ++s) {
    float bdv = 3.3e38f; int bix = 0x7fffffff; int bc = 0;
    #pragma unroll
    for (int c = 0; c < 8; ++c) {
      if (h[c] < 16) {
        float dd = pd[base + c * 16 + h[c]];
        int   ii = pi[base + c * 16 + h[c]];
        if (dd < bdv || (dd == bdv && ii < bix)) { bdv = dd; bix = ii; bc = c; }
      }
    }
    idxb[(size_t)g * 16 + s] = (u16t)bix;
    h[bc]++;
  }
}

// ----------------------------------------------------------- K/V GEMM (MFMA)
// 64-row block, full K=256 staged once in LDS (bf16), B-frags from L2.
__global__ __launch_bounds__(256) void gemm_kv_mfma(const float* __restrict__ feat,
    const u16t* __restrict__ frags,
    const float* __restrict__ bk, const float* __restrict__ bv,
    u16t* __restrict__ kb, u16t* __restrict__ vb) {
  int mat = blockIdx.y;
  const u16t* wf   = frags + (size_t)mat * 65536;
  const float* bias = mat ? bv : bk;
  u16t* out         = mat ? vb : kb;

  int rbase = blockIdx.x * 64;
  int tid = threadIdx.x, lane = tid & 63, wvi = tid >> 6;
  int quad = lane >> 4, l15 = lane & 15;

  alignas(16) __shared__ u16t featS[64 * 264];

  // stage feat rows (f32 -> bf16)
  {
    int r = tid >> 2, c0 = (tid & 3) * 64;
    const float* src = feat + (size_t)(rbase + r) * DMODEL + c0;
    u16t* dst = featS + r * 264 + c0;
    #pragma unroll
    for (int t = 0; t < 8; ++t) {
      float4 a = *(const float4*)(src + t * 8);
      float4 b = *(const float4*)(src + t * 8 + 4);
      float o[8] = {a.x, a.y, a.z, a.w, b.x, b.y, b.z, b.w};
      *(uint4*)(dst + t * 8) = pack8(o);
    }
  }
  __syncthreads();

  floatx4 acc[16];
  #pragma unroll
  for (int ct = 0; ct < 16; ++ct) acc[ct] = (floatx4){0.f, 0.f, 0.f, 0.f};

  #pragma unroll
  for (int ic = 0; ic < 8; ++ic) {
    short8 af = *(const short8*)(featS + (wvi * 16 + l15) * 264 + ic * 32 + quad * 8);
    #pragma unroll
    for (int ct = 0; ct < 16; ++ct) {
      short8 bf = *(const short8*)(wf + (((size_t)(ic * 16 + ct) * 64 + lane) << 3));
      acc[ct] = __builtin_amdgcn_mfma_f32_16x16x32_bf16(af, bf, acc[ct], 0, 0, 0);
    }
  }

  #pragma unroll
  for (int ct = 0; ct < 16; ++ct) {
    int col = ct * 16 + l15;
    float bvv = bias[col];
    #pragma unroll
    for (int r = 0; r < 4; ++r) {
      int row = rbase + wvi * 16 + quad * 4 + r;
      out[(size_t)row * DMODEL + col] = f2b(acc[ct][r] + bvv);
    }
  }
}

// -------------------------------------------------------------- mega kernel
// v3: B-frags streamed from L2 (low VGPR, high occupancy).
#define HSTR 264
__global__ __launch_bounds__(256, 4) void attn_mega(
    const float* __restrict__ coords, const float* __restrict__ normals,
    const float* __restrict__ maskp, const float* __restrict__ feat,
    const float* __restrict__ Wq, const float* __restrict__ bq,
    const float* __restrict__ Wp1, const float* __restrict__ bp1,
    const float* __restrict__ bp2,
    const float* __restrict__ Wo, const float* __restrict__ bo,
    const float* __restrict__ gamma, const float* __restrict__ beta,
    const u16t* __restrict__ idxp, const u16t* __restrict__ wp2frag,
    const u16t* __restrict__ kbuf, const u16t* __restrict__ vbuf,
    float* __restrict__ outp) {
  alignas(16) __shared__ u16t  hemb[16 * HSTR];     // hidT then embS (aliased)
  alignas(16) __shared__ float featall[8 * DMODEL];
  alignas(16) __shared__ float oall[8 * DMODEL];
  alignas(16) __shared__ float lgs[8 * 16];
  __shared__ float red[4], red2[4];

  int c    = threadIdx.x;
  int lane = c & 63;
  int wv   = c >> 6;
  int quad = lane >> 4;
  int l15  = lane & 15;
  int hh   = c >> 5;
  int wv4  = wv * 4;

  float w1[6];
  #pragma unroll
  for (int p = 0; p < 6; ++p) w1[p] = Wp1[p * DMODEL + c];
  float b1v = bp1[c];
  float b2v = bp2[c];
  float bqv = bq[c];
  float bov = bo[c];
  float gam = gamma[c];
  float bet = beta[c];

  int qbase = blockIdx.x * 8;

  #pragma unroll
  for (int qi = 0; qi < 8; ++qi)
    featall[qi * DMODEL + c] = feat[(size_t)(qbase + qi) * DMODEL + c];
  __syncthreads();

  // q projection for all 8 queries (Wq read once per block)
  float qreg[8];
  #pragma unroll
  for (int qi = 0; qi < 8; ++qi) qreg[qi] = bqv;
  for (int d = 0; d < DMODEL; d += 4) {
    float wa = Wq[(size_t)(d + 0) * DMODEL + c];
    float wb = Wq[(size_t)(d + 1) * DMODEL + c];
    float wc = Wq[(size_t)(d + 2) * DMODEL + c];
    float wd = Wq[(size_t)(d + 3) * DMODEL + c];
    #pragma unroll
    for (int qi = 0; qi < 8; ++qi) {
      qreg[qi] += featall[qi * DMODEL + d + 0] * wa;
      qreg[qi] += featall[qi * DMODEL + d + 1] * wb;
      qreg[qi] += featall[qi * DMODEL + d + 2] * wc;
      qreg[qi] += featall[qi * DMODEL + d + 3] * wd;
    }
  }

  const float lsc = 0.17677669529663687f;

  for (int qi = 0; qi < 8; ++qi) {
    int g = qbase + qi;
    int bb0 = (g >> 13) * NPTS;

    float qx = coords[(size_t)g * 3 + 0];
    float qy = coords[(size_t)g * 3 + 1];
    float qz = coords[(size_t)g * 3 + 2];
    float n0 = normals[(size_t)g * 3 + 0];
    float n1 = normals[(size_t)g * 3 + 1];
    float n2 = normals[(size_t)g * 3 + 2];

    int ids[16];
    float hreg[16];
    #pragma unroll
    for (int j = 0; j < 16; ++j) {
      int id = (int)idxp[(size_t)g * 16 + j];
      ids[j] = id;
      size_t cb = (size_t)(bb0 + id) * 3;
      float rx = qx - coords[cb + 0];
      float ry = qy - coords[cb + 1];
      float rz = qz - coords[cb + 2];
      float pre = b1v + rx * w1[0] + ry * w1[1] + rz * w1[2]
                      + n0 * w1[3] + n1 * w1[4] + n2 * w1[5];
      hreg[j] = gelu_exact(pre);
    }

    __syncthreads();   // sync1
    #pragma unroll
    for (int j = 0; j < 16; ++j) hemb[j * HSTR + c] = f2b(hreg[j]);
    __syncthreads();   // sync2

    short8 afrag[8];
    {
      const u16t* ap = hemb + l15 * HSTR + quad * 8;
      #pragma unroll
      for (int ic = 0; ic < 8; ++ic) afrag[ic] = *(const short8*)(ap + ic * 32);
    }
    __syncthreads();   // sync3

    floatx4 acc[4];
    #pragma unroll
    for (int cc = 0; cc < 4; ++cc) acc[cc] = (floatx4){0.f, 0.f, 0.f, 0.f};
    #pragma unroll
    for (int ic = 0; ic < 8; ++ic) {
      #pragma unroll
      for (int cc = 0; cc < 4; ++cc) {
        short8 bf = *(const short8*)(wp2frag + (((size_t)(ic * 16 + wv4 + cc) * 64 + lane) << 3));
        acc[cc] = __builtin_amdgcn_mfma_f32_16x16x32_bf16(afrag[ic], bf, acc[cc], 0, 0, 0);
      }
    }
    #pragma unroll
    for (int cc = 0; cc < 4; ++cc) {
      int cg = (wv4 + cc) * 16 + l15;
      #pragma unroll
      for (int r = 0; r < 4; ++r)
        hemb[(quad * 4 + r) * HSTR + cg] = f2b(acc[cc][r]);
    }
    __syncthreads();   // sync4

    float emb[16];
    #pragma unroll
    for (int j = 0; j < 16; ++j) emb[j] = b2f(hemb[j * HSTR + c]) + b2v;

    float qv = qreg[qi];
    #pragma unroll
    for (int j = 0; j < 16; ++j) {
      float kc = b2f(kbuf[(size_t)(bb0 + ids[j]) * DMODEL + c]) + emb[j];
      float p = qv * kc;
      p += __shfl_xor(p, 16, 32);
      p += __shfl_xor(p, 8, 32);
      p += __shfl_xor(p, 4, 32);
      p += __shfl_xor(p, 2, 32);
      p += __shfl_xor(p, 1, 32);
      if ((c & 31) == 0) {
        float mv = maskp[bb0 + ids[j]];
        lgs[hh * 16 + j] = (mv > 0.0f) ? (p * lsc) : -1e30f;
      }
    }
    __syncthreads();   // sync5

    float lg[16];
    #pragma unroll
    for (int j = 0; j < 16; ++j) lg[j] = lgs[hh * 16 + j];
    float m = lg[0];
    #pragma unroll
    for (int j = 1; j < 16; ++j) m = fmaxf(m, lg[j]);
    float wj[16];
    if (m > -1e29f) {
      float s = 0.0f;
      #pragma unroll
      for (int j = 0; j < 16; ++j) { wj[j] = expf(lg[j] - m); s += wj[j]; }
      float inv = 1.0f / s;
      #pragma unroll
      for (int j = 0; j < 16; ++j) wj[j] *= inv;
    } else {
      #pragma unroll
      for (int j = 0; j < 16; ++j) wj[j] = 0.0f;
    }
    float o = 0.0f;
    #pragma unroll
    for (int j = 0; j < 16; ++j)
      o += wj[j] * (b2f(vbuf[(size_t)(bb0 + ids[j]) * DMODEL + c]) + emb[j]);
    oall[qi * DMODEL + c] = o;
  }
  __syncthreads();

  // out projection (Wo read once per block)
  float po[8];
  #pragma unroll
  for (int qi = 0; qi < 8; ++qi) po[qi] = 0.0f;
  for (int d = 0; d < DMODEL; d += 4) {
    float wa = Wo[(size_t)(d + 0) * DMODEL + c];
    float wb = Wo[(size_t)(d + 1) * DMODEL + c];
    float wc = Wo[(size_t)(d + 2) * DMODEL + c];
    float wd = Wo[(size_t)(d + 3) * DMODEL + c];
    #pragma unroll
    for (int qi = 0; qi < 8; ++qi) {
      po[qi] += oall[qi * DMODEL + d + 0] * wa;
      po[qi] += oall[qi * DMODEL + d + 1] * wb;
      po[qi] += oall[qi * DMODEL + d + 2] * wc;
      po[qi] += oall[qi * DMODEL + d + 3] * wd;
    }
  }

  // residual + LayerNorm + mask; f32 store
  for (int qi = 0; qi < 8; ++qi) {
    int g = qbase + qi;
    float mv = maskp[g];
    float h = featall[qi * DMODEL + c] + (po[qi] + bov) * mv;
    float s = h, s2 = h * h;
    #pragma unroll
    for (int off = 32; off > 0; off >>= 1) {
      s  += __shfl_down(s,  off);
      s2 += __shfl_down(s2, off);
    }
    __syncthreads();
    if ((c & 63) == 0) { red[c >> 6] = s; red2[c >> 6] = s2; }
    __syncthreads();
    float mu  = (red[0]  + red[1]  + red[2]  + red[3])  * (1.0f / 256.0f);
    float ms  = (red2[0] + red2[1] + red2[2] + red2[3]) * (1.0f / 256.0f);
    float var = ms - mu * mu;
    float y = (h - mu) / sqrtf(var + 1e-6f) * gam + bet;
    y *= mv;
    outp[(size_t)g * DMODEL + c] = y;
  }
}

// ---------------------------------------------------------------------- host
extern "C" void kernel_launch(void* const* d_in, const int* in_sizes, int n_in,
                              void* d_out, int out_size, void* d_ws, size_t ws_size,
                              hipStream_t stream) {
  static const int EXP[18] = {4194304, 49152, 49152, 16384,
                              65536, 256, 65536, 256, 65536, 256, 65536, 256,
                              1536, 256, 65536, 256, 256, 256};
  bool sizes_ok = (n_in >= 18);
  if (sizes_ok) for (int i = 0; i < 18; ++i) sizes_ok = sizes_ok && (in_sizes[i] == EXP[i]);
  int fb = (out_size + 255) / 256;
  if (!sizes_ok) {
    fill_valf<<<fb, 256, 0, stream>>>((float*)d_out, out_size, 0.0f);
    return;
  }
  const size_t WS_NEED = 17825792;
  if (ws_size < WS_NEED) {
    fill_valf<<<fb, 256, 0, stream>>>((float*)d_out, out_size, 1.0f);
    return;
  }

  const float* feat    = (const float*)d_in[0];
  const float* coords  = (const float*)d_in[1];
  const float* normals = (const float*)d_in[2];
  const float* maskp   = (const float*)d_in[3];
  const float* Wq  = (const float*)d_in[4];
  const float* bq  = (const float*)d_in[5];
  const float* Wk  = (const float*)d_in[6];
  const float* bk  = (const float*)d_in[7];
  const float* Wv  = (const float*)d_in[8];
  const float* bv  = (const float*)d_in[9];
  const float* Wo  = (const float*)d_in[10];
  const float* bo  = (const float*)d_in[11];
  const float* Wp1 = (const float*)d_in[12];
  const float* bp1 = (const float*)d_in[13];
  const float* Wp2 = (const float*)d_in[14];
  const float* bp2 = (const float*)d_in[15];
  const float* gamma = (const float*)d_in[16];
  const float* beta  = (const float*)d_in[17];

  // Workspace (<= 17,825,792 B, proven):
  //   idx16 : u16 [16384*16]      @ 0         (524,288)
  //   frags : bf16 [3*65536]      @ 524,288   (393,216)  (Wk,Wv,Wp2)
  //   kb    : bf16 [16384*256]    @ 917,504   (8,388,608)
  //   vb    : bf16 [16384*256]    @ 9,306,112 (8,388,608)  end 17,694,720
  //   pd/pi (kNN partials, 16 MB) alias kb+vb: dead before gemm_kv_mfma.
  char* ws = (char*)d_ws;
  u16t*  idx16 = (u16t*)(ws);
  u16t*  frags = (u16t*)(ws + 524288);
  u16t*  kb    = (u16t*)(ws + 917504);
  u16t*  vb    = (u16t*)(ws + 9306112);
  float* pd    = (float*)(ws + 917504);
  int*   pi    = (int*)(ws + 9306112);

  wprep<<<768, 256, 0, stream>>>(Wk, Wv, Wp2, frags);
  knn_partial<<<512, 256, 0, stream>>>(coords, pd, pi);
  knn_merge<<<64, 256, 0, stream>>>(pd, pi, idx16);
  gemm_kv_mfma<<<dim3(256, 2), 256, 0, stream>>>(feat, frags, bk, bv, kb, vb);
  attn_mega<<<2048, 256, 0, stream>>>(coords, normals, maskp, feat,
                                      Wq, bq, Wp1, bp1, bp2, Wo, bo,
                                      gamma, beta, idx16, frags + 2 * 65536, kb, vb,
                                      (float*)d_out);
}